// Round 5
// baseline (363.494 us; speedup 1.0000x reference)
//
#include <hip/hip_runtime.h>
#include <math.h>

#define N_NODES 200000
#define E_EDGES 100000
#define TIME_DIM 100
#define RAW_DIM 484   // 128 + 128 + 128 + 100

typedef short  bf16x8 __attribute__((ext_vector_type(8)));
typedef float  f32x4  __attribute__((ext_vector_type(4)));

__device__ __forceinline__ short f2bf(float f) {
    unsigned u = __builtin_bit_cast(unsigned, f);
    u = (u + 0x7FFFu + ((u >> 16) & 1u)) >> 16;   // RNE
    return (short)u;
}
__device__ __forceinline__ float bf2f(unsigned short u) {
    return __builtin_bit_cast(float, ((unsigned)u) << 16);
}
__device__ __forceinline__ float fsigmoid(float x) {
    return __builtin_amdgcn_rcpf(1.0f + __expf(-x));
}
__device__ __forceinline__ float ftanh(float x) {
    float t = __expf(2.0f * x);
    return 1.0f - 2.0f * __builtin_amdgcn_rcpf(t + 1.0f);
}
__device__ __forceinline__ void atomic_pk_add_bf16(short* addr, unsigned v) {
    asm volatile("global_atomic_pk_add_bf16 %0, %1, off" :: "v"(addr), "v"(v) : "memory");
}
// pack 8 consecutive f32 -> 8 consecutive bf16 (RNE via v_cvt_pk_bf16_f32)
__device__ __forceinline__ bf16x8 pack8(float4 a, float4 b) {
    unsigned r0, r1, r2, r3;
    asm("v_cvt_pk_bf16_f32 %0, %1, %2" : "=v"(r0) : "v"(a.x), "v"(a.y));
    asm("v_cvt_pk_bf16_f32 %0, %1, %2" : "=v"(r1) : "v"(a.z), "v"(a.w));
    asm("v_cvt_pk_bf16_f32 %0, %1, %2" : "=v"(r2) : "v"(b.x), "v"(b.y));
    asm("v_cvt_pk_bf16_f32 %0, %1, %2" : "=v"(r3) : "v"(b.z), "v"(b.w));
    uint4 u = {r0, r1, r2, r3};
    return __builtin_bit_cast(bf16x8, u);
}

// ---------------------------------------------------------------------------
// Prep 1: pack msg_W [128][484] -> bf16 B-fragment order, K padded to 512.
// wfm[t][s][l][j]: element = msg_W[t*16+(l&15)][s*32+(l>>4)*8+j]
// ---------------------------------------------------------------------------
__global__ __launch_bounds__(256) void tgn_prep_wmsg(
    const float* __restrict__ msgW, short* __restrict__ wf)
{
    int idx = blockIdx.x * 256 + threadIdx.x;   // 0 .. 65535
    int j = idx & 7;
    int l = (idx >> 3) & 63;
    int s = (idx >> 9) & 15;
    int t = idx >> 13;
    int n = t * 16 + (l & 15);
    int k = s * 32 + (l >> 4) * 8 + j;
    float v = (k < RAW_DIM) ? msgW[(size_t)n * RAW_DIM + k] : 0.0f;
    wf[idx] = f2bf(v);
}

// ---------------------------------------------------------------------------
// Prep 2: pack combined GRU weight matrix W_big[512][256] into B-frag order.
// ---------------------------------------------------------------------------
__global__ __launch_bounds__(256) void tgn_prep_wgru(
    const float* __restrict__ Wih, const float* __restrict__ Whh,
    short* __restrict__ wf)
{
    int idx = blockIdx.x * 256 + threadIdx.x;   // 0 .. 131071
    int j = idx & 7;
    int l = (idx >> 3) & 63;
    int s = (idx >> 9) & 7;
    int t = idx >> 12;
    int n = t * 16 + (l & 15);
    int k = s * 32 + (l >> 4) * 8 + j;
    int half = k >> 7;
    int kk = k & 127;
    float v;
    if (n < 256) {
        v = half ? Whh[(size_t)n * 128 + kk] : Wih[(size_t)n * 128 + kk];
    } else if (n < 384) {
        v = half ? 0.0f : Wih[(size_t)n * 128 + kk];
    } else {
        v = half ? Whh[(size_t)(n - 128) * 128 + kk] : 0.0f;
    }
    wf[idx] = f2bf(v);
}

// ---------------------------------------------------------------------------
// Kernel A: register-gather MFMA message MLP + scatter-add.
// 128 threads = 2 waves; each wave owns 16 edges x all 128 outputs.
// A-fragments gathered straight to registers (no LDS, no barriers):
//   lane l -> edge row (l&15), k-chunk (l>>4)*8 within each 32-k window.
//   s=0..3: memory[sid], s=4..7: memory[did], s=8..11: edge_feat,
//   s=12..15: cos time encoding on VALU (k>=484 -> 0).
// ---------------------------------------------------------------------------
#define MTE 32   // edges per block (2 waves x 16)

template<bool PK>
__global__ __launch_bounds__(128, 2) void tgn_msg_mfma(
    const float* __restrict__ memory,
    const float* __restrict__ last_update,
    const float* __restrict__ timestamps,
    const float* __restrict__ edge_features,
    const float* __restrict__ msg_b,
    const float* __restrict__ time_w,
    const float* __restrict__ time_b,
    const int*   __restrict__ src,
    const int*   __restrict__ dst,
    const short* __restrict__ wfm,
    short* __restrict__ sums_bf,
    float* __restrict__ sums_f,
    float* __restrict__ counts)
{
    const int tid  = threadIdx.x;
    const int wv   = tid >> 6;
    const int l    = tid & 63;
    const int lrow = l & 15;
    const int lkg  = l >> 4;
    const int e0   = blockIdx.x * MTE + wv * 16;  // wave's edge base
    const int e    = e0 + lrow;                   // this lane's gather edge

    const int sid = src[e];
    const int did = dst[e];
    const float dt = timestamps[e] - last_update[sid];

    if (lkg == 0) {
        atomicAdd(&counts[sid], 1.0f);
        atomicAdd(&counts[did], 1.0f);
    }

    // ---- issue all gathers (24 independent dwordx4 per lane) ----
    const float* srcm = memory        + (size_t)sid * 128 + lkg * 8;
    const float* dstm = memory        + (size_t)did * 128 + lkg * 8;
    const float* ef   = edge_features + (size_t)e   * 128 + lkg * 8;
    float4 bufS[8], bufD[8], bufE[8];
#pragma unroll
    for (int s = 0; s < 4; ++s) {
        bufS[2 * s]     = *reinterpret_cast<const float4*>(srcm + s * 32);
        bufS[2 * s + 1] = *reinterpret_cast<const float4*>(srcm + s * 32 + 4);
        bufD[2 * s]     = *reinterpret_cast<const float4*>(dstm + s * 32);
        bufD[2 * s + 1] = *reinterpret_cast<const float4*>(dstm + s * 32 + 4);
        bufE[2 * s]     = *reinterpret_cast<const float4*>(ef + s * 32);
        bufE[2 * s + 1] = *reinterpret_cast<const float4*>(ef + s * 32 + 4);
    }

    // ---- time-encoding chunks on VALU while loads are in flight ----
    bf16x8 afr[16];
#pragma unroll
    for (int s = 12; s < 16; ++s) {
        int k0 = s * 32 + lkg * 8;
        float4 lo, hi;
        float* p = &lo.x;
#pragma unroll
        for (int j = 0; j < 8; ++j) {
            int k = k0 + j;
            float v = 0.0f;
            if (k < RAW_DIM) {
                int t = k - 384;
                v = __cosf(fmaf(dt, time_w[t], time_b[t]));
            }
            if (j < 4) (&lo.x)[j] = v; else (&hi.x)[j - 4] = v;
        }
        (void)p;
        afr[s] = pack8(lo, hi);
    }

    // ---- convert gathered chunks (compiler inserts counted vmcnt) ----
#pragma unroll
    for (int s = 0; s < 4; ++s) {
        afr[s]     = pack8(bufS[2 * s], bufS[2 * s + 1]);
        afr[4 + s] = pack8(bufD[2 * s], bufD[2 * s + 1]);
        afr[8 + s] = pack8(bufE[2 * s], bufE[2 * s + 1]);
    }

    // ---- MFMA: 16 k-steps x 8 output tiles ----
    f32x4 acc[8];
#pragma unroll
    for (int t = 0; t < 8; ++t) acc[t] = (f32x4){0.f, 0.f, 0.f, 0.f};

#pragma unroll
    for (int s = 0; s < 16; ++s) {
#pragma unroll
        for (int t = 0; t < 8; ++t) {
            bf16x8 B = *reinterpret_cast<const bf16x8*>(
                &wfm[(size_t)(((t * 16 + s) * 64) + l) * 8]);
            acc[t] = __builtin_amdgcn_mfma_f32_16x16x32_bf16(afr[s], B, acc[t], 0, 0, 0);
        }
    }

    // ---- epilogue: bias + scatter-add to both endpoints ----
    const bool even = (l & 1) == 0;
#pragma unroll
    for (int r = 0; r < 4; ++r) {
        int el = lkg * 4 + r;              // edge row of this C element
        int sN = __shfl(sid, el);          // from lane el (lrow=el, lkg=0)
        int dN = __shfl(did, el);
#pragma unroll
        for (int t = 0; t < 8; ++t) {
            int j = t * 16 + lrow;
            float m = acc[t][r] + msg_b[j];
            if (PK) {
                float mo = __shfl_xor(m, 1);
                unsigned mb  = (unsigned short)f2bf(m);
                unsigned mob = (unsigned short)f2bf(mo);
                unsigned pk = even ? (mb | (mob << 16)) : (mob | (mb << 16));
                int node = even ? sN : dN;
                atomic_pk_add_bf16(&sums_bf[(size_t)node * 128 + (j & ~1)], pk);
            } else {
                atomicAdd(&sums_f[(size_t)sN * 128 + j], m);
                atomicAdd(&sums_f[(size_t)dN * 128 + j], m);
            }
        }
    }
}

// ---------------------------------------------------------------------------
// Kernel B: fused MFMA GEMM + GRU gates.  32 nodes/block, 256 threads.
// ---------------------------------------------------------------------------
#define GNT 32

template<bool PK>
__global__ __launch_bounds__(256, 3) void tgn_gru_mfma(
    const float* __restrict__ memory,
    const float* __restrict__ last_update,
    const float* __restrict__ timestamps,
    const float* __restrict__ b_ih,
    const float* __restrict__ b_hh,
    const short* __restrict__ wfrag,
    const short* __restrict__ sums_bf,
    const float* __restrict__ sums_f,
    const float* __restrict__ counts,
    float* __restrict__ out)
{
    __shared__ short X[GNT][264];
    __shared__ float cntS[GNT];

    const int tid = threadIdx.x;
    const int n0 = blockIdx.x * GNT;

    if (tid < GNT) cntS[tid] = counts[n0 + tid];
    __syncthreads();

    for (int i = tid; i < GNT * 32; i += 256) {
        int m = i >> 5;
        int c = (i & 31) * 4;
        float inv = 1.0f / fmaxf(cntS[m], 1.0f);
        short4 a4;
        if (PK) {
            ushort4 u = *reinterpret_cast<const ushort4*>(&sums_bf[(size_t)(n0 + m) * 128 + c]);
            a4.x = f2bf(bf2f(u.x) * inv);
            a4.y = f2bf(bf2f(u.y) * inv);
            a4.z = f2bf(bf2f(u.z) * inv);
            a4.w = f2bf(bf2f(u.w) * inv);
        } else {
            float4 v = *reinterpret_cast<const float4*>(&sums_f[(size_t)(n0 + m) * 128 + c]);
            a4.x = f2bf(v.x * inv);
            a4.y = f2bf(v.y * inv);
            a4.z = f2bf(v.z * inv);
            a4.w = f2bf(v.w * inv);
        }
        *reinterpret_cast<short4*>(&X[m][c]) = a4;
        float4 mv = *reinterpret_cast<const float4*>(&memory[(size_t)(n0 + m) * 128 + c]);
        short4 m4;
        m4.x = f2bf(mv.x); m4.y = f2bf(mv.y); m4.z = f2bf(mv.z); m4.w = f2bf(mv.w);
        *reinterpret_cast<short4*>(&X[m][128 + c]) = m4;
    }
    __syncthreads();

    const int w    = tid >> 6;
    const int l    = tid & 63;
    const int lrow = l & 15;
    const int lkg  = l >> 4;

    f32x4 acc[4][2][2];   // [quadrant][jt][mt]
#pragma unroll
    for (int q = 0; q < 4; q++)
#pragma unroll
        for (int jt = 0; jt < 2; jt++)
#pragma unroll
            for (int mt = 0; mt < 2; mt++)
                acc[q][jt][mt] = (f32x4){0.f, 0.f, 0.f, 0.f};

    for (int s = 0; s < 8; ++s) {
        bf16x8 A[2];
#pragma unroll
        for (int mt = 0; mt < 2; ++mt)
            A[mt] = *reinterpret_cast<const bf16x8*>(&X[mt * 16 + lrow][s * 32 + lkg * 8]);
#pragma unroll
        for (int q = 0; q < 4; ++q)
#pragma unroll
            for (int jt = 0; jt < 2; ++jt) {
                int t = q * 8 + w * 2 + jt;
                bf16x8 B = *reinterpret_cast<const bf16x8*>(&wfrag[(size_t)(((t * 8 + s) * 64) + l) * 8]);
#pragma unroll
                for (int mt = 0; mt < 2; ++mt)
                    acc[q][jt][mt] = __builtin_amdgcn_mfma_f32_16x16x32_bf16(
                        A[mt], B, acc[q][jt][mt], 0, 0, 0);
            }
    }

    const float ts0 = timestamps[0];

#pragma unroll
    for (int jt = 0; jt < 2; ++jt) {
        int j = w * 32 + jt * 16 + lrow;
        float br  = b_ih[j]       + b_hh[j];
        float bz  = b_ih[128 + j] + b_hh[128 + j];
        float bin = b_ih[256 + j];
        float bhn = b_hh[256 + j];
#pragma unroll
        for (int mt = 0; mt < 2; ++mt) {
#pragma unroll
            for (int r = 0; r < 4; ++r) {
                int mloc = mt * 16 + lkg * 4 + r;
                int node = n0 + mloc;
                float rg  = acc[0][jt][mt][r] + br;
                float zg  = acc[1][jt][mt][r] + bz;
                float ing = acc[2][jt][mt][r] + bin;
                float hng = acc[3][jt][mt][r] + bhn;
                float rr = fsigmoid(rg);
                float zz = fsigmoid(zg);
                float nn = ftanh(ing + rr * hng);
                float mv = memory[(size_t)node * 128 + j];
                float h  = (1.0f - zz) * nn + zz * mv;
                out[(size_t)node * 128 + j] = (cntS[mloc] > 0.0f) ? h : mv;
            }
        }
    }

    if (tid < GNT) {
        int node = n0 + tid;
        out[(size_t)N_NODES * 128 + node] = (cntS[tid] > 0.0f) ? ts0 : last_update[node];
    }
}

// ---------------------------------------------------------------------------
extern "C" void kernel_launch(void* const* d_in, const int* in_sizes, int n_in,
                              void* d_out, int out_size, void* d_ws, size_t ws_size,
                              hipStream_t stream) {
    const float* memory        = (const float*)d_in[0];
    const float* last_update   = (const float*)d_in[1];
    const float* timestamps    = (const float*)d_in[2];
    const float* edge_features = (const float*)d_in[3];
    const float* msg_W         = (const float*)d_in[4];
    const float* msg_b         = (const float*)d_in[5];
    const float* gru_W_ih      = (const float*)d_in[6];
    const float* gru_W_hh      = (const float*)d_in[7];
    const float* gru_b_ih      = (const float*)d_in[8];
    const float* gru_b_hh      = (const float*)d_in[9];
    const float* time_w        = (const float*)d_in[10];
    const float* time_b        = (const float*)d_in[11];
    const int*   src           = (const int*)d_in[12];
    const int*   dst           = (const int*)d_in[13];

    float* out = (float*)d_out;
    short* wfrag_gru = (short*)d_ws;            // 131072 bf16 = 256 KB
    short* wfrag_msg = (short*)d_ws + 131072;   //  65536 bf16 = 128 KB

    short* sums_bf   = (short*)d_ws + 196608;
    float* counts_ws = (float*)((char*)d_ws + 393216 + (size_t)N_NODES * 128 * 2);
    const size_t ws_needed = 393216 + (size_t)N_NODES * 128 * 2 + (size_t)N_NODES * 4;

    tgn_prep_wgru<<<512, 256, 0, stream>>>(gru_W_ih, gru_W_hh, wfrag_gru);
    tgn_prep_wmsg<<<256, 256, 0, stream>>>(msg_W, wfrag_msg);

    if (ws_size >= ws_needed) {
        hipMemsetAsync(sums_bf, 0, (size_t)N_NODES * 128 * 2 + (size_t)N_NODES * 4, stream);

        tgn_msg_mfma<true><<<E_EDGES / MTE, 128, 0, stream>>>(
            memory, last_update, timestamps, edge_features, msg_b,
            time_w, time_b, src, dst, wfrag_msg, sums_bf, nullptr, counts_ws);

        tgn_gru_mfma<true><<<N_NODES / GNT, 256, 0, stream>>>(
            memory, last_update, timestamps, gru_b_ih, gru_b_hh, wfrag_gru,
            sums_bf, nullptr, counts_ws, out);
    } else {
        hipMemsetAsync(d_out, 0, (size_t)out_size * sizeof(float), stream);
        float* sums_f = out;
        float* counts = out + (size_t)N_NODES * 128;

        tgn_msg_mfma<false><<<E_EDGES / MTE, 128, 0, stream>>>(
            memory, last_update, timestamps, edge_features, msg_b,
            time_w, time_b, src, dst, wfrag_msg, nullptr, sums_f, counts);

        tgn_gru_mfma<false><<<N_NODES / GNT, 256, 0, stream>>>(
            memory, last_update, timestamps, gru_b_ih, gru_b_hh, wfrag_gru,
            nullptr, sums_f, counts, out);
    }
}

// Round 7
// 332.818 us; speedup vs baseline: 1.0922x; 1.0922x over previous
//
#include <hip/hip_runtime.h>
#include <math.h>

#define N_NODES 200000
#define E_EDGES 100000
#define TIME_DIM 100
#define RAW_DIM 484   // 128 + 128 + 128 + 100

typedef short  bf16x8 __attribute__((ext_vector_type(8)));
typedef float  f32x4  __attribute__((ext_vector_type(4)));

__device__ __forceinline__ short f2bf(float f) {
    unsigned u = __builtin_bit_cast(unsigned, f);
    u = (u + 0x7FFFu + ((u >> 16) & 1u)) >> 16;   // RNE
    return (short)u;
}
__device__ __forceinline__ float fsigmoid(float x) {
    return __builtin_amdgcn_rcpf(1.0f + __expf(-x));
}
__device__ __forceinline__ float ftanh(float x) {
    float t = __expf(2.0f * x);
    return 1.0f - 2.0f * __builtin_amdgcn_rcpf(t + 1.0f);
}

// ---------------------------------------------------------------------------
// Prep 1: pack msg_W [128][484] -> bf16 B-fragment order, K padded to 512.
// wfm[t][s][l][j]: element = msg_W[t*16+(l&15)][s*32+(l>>4)*8+j]
// ---------------------------------------------------------------------------
__global__ __launch_bounds__(256) void tgn_prep_wmsg(
    const float* __restrict__ msgW, short* __restrict__ wf)
{
    int idx = blockIdx.x * 256 + threadIdx.x;   // 0 .. 65535
    int j = idx & 7;
    int l = (idx >> 3) & 63;
    int s = (idx >> 9) & 15;
    int t = idx >> 13;
    int n = t * 16 + (l & 15);
    int k = s * 32 + (l >> 4) * 8 + j;
    float v = (k < RAW_DIM) ? msgW[(size_t)n * RAW_DIM + k] : 0.0f;
    wf[idx] = f2bf(v);
}

// ---------------------------------------------------------------------------
// Prep 2: pack combined GRU weight matrix W_big[512][256] into B-frag order.
//   n in [0,128):   r   -> [W_ih[n] | W_hh[n]]
//   n in [128,256): z   -> [W_ih[n] | W_hh[n]]
//   n in [256,384): i_n -> [W_ih[n] | 0      ]
//   n in [384,512): h_n -> [0       | W_hh[n-128]]
// ---------------------------------------------------------------------------
__global__ __launch_bounds__(256) void tgn_prep_wgru(
    const float* __restrict__ Wih, const float* __restrict__ Whh,
    short* __restrict__ wf)
{
    int idx = blockIdx.x * 256 + threadIdx.x;   // 0 .. 131071
    int j = idx & 7;
    int l = (idx >> 3) & 63;
    int s = (idx >> 9) & 7;
    int t = idx >> 12;
    int n = t * 16 + (l & 15);
    int k = s * 32 + (l >> 4) * 8 + j;
    int half = k >> 7;
    int kk = k & 127;
    float v;
    if (n < 256) {
        v = half ? Whh[(size_t)n * 128 + kk] : Wih[(size_t)n * 128 + kk];
    } else if (n < 384) {
        v = half ? 0.0f : Wih[(size_t)n * 128 + kk];
    } else {
        v = half ? Whh[(size_t)(n - 128) * 128 + kk] : 0.0f;
    }
    wf[idx] = f2bf(v);
}

// ---------------------------------------------------------------------------
// Kernel A: MFMA message MLP + f32 atomic scatter-add into sums/counts
// (both live in d_out).  32 edges/block, 256 threads = 4 waves.
// wave w: edge-tile et=w&1 (16 edges), output-half nh=w>>1 (64 outputs).
// (verbatim round-3 structure — proven ~110 us)
// ---------------------------------------------------------------------------
#define TE 32

__global__ __launch_bounds__(256, 2) void tgn_msg_mfma(
    const float* __restrict__ memory,
    const float* __restrict__ last_update,
    const float* __restrict__ timestamps,
    const float* __restrict__ edge_features,
    const float* __restrict__ msg_b,
    const float* __restrict__ time_w,
    const float* __restrict__ time_b,
    const int*   __restrict__ src,
    const int*   __restrict__ dst,
    const short* __restrict__ wfm,
    float* __restrict__ sums,
    float* __restrict__ counts)
{
    __shared__ short X[TE][520];    // 33,280 B
    __shared__ int   sid[TE];
    __shared__ int   did[TE];
    __shared__ float dtS[TE];

    const int tid = threadIdx.x;
    const int e0  = blockIdx.x * TE;

    if (tid < TE) {
        int s = src[e0 + tid];
        int d = dst[e0 + tid];
        sid[tid] = s;
        did[tid] = d;
        dtS[tid] = timestamps[e0 + tid] - last_update[s];
        atomicAdd(&counts[s], 1.0f);
        atomicAdd(&counts[d], 1.0f);
    }
    __syncthreads();

    // Stage raw as bf16: 32 rows x 128 float4-chunks (k 484..511 zero-padded)
    for (int i = tid; i < TE * 128; i += 256) {
        int e = i >> 7;
        int c = (i & 127) * 4;
        float4 v;
        if (c < 128) {
            v = *reinterpret_cast<const float4*>(&memory[(size_t)sid[e] * 128 + c]);
        } else if (c < 256) {
            v = *reinterpret_cast<const float4*>(&memory[(size_t)did[e] * 128 + (c - 128)]);
        } else if (c < 384) {
            v = *reinterpret_cast<const float4*>(&edge_features[(size_t)(e0 + e) * 128 + (c - 256)]);
        } else if (c < 484) {
            float dt = dtS[e];
            int t = c - 384;
            v.x = __cosf(fmaf(dt, time_w[t + 0], time_b[t + 0]));
            v.y = __cosf(fmaf(dt, time_w[t + 1], time_b[t + 1]));
            v.z = __cosf(fmaf(dt, time_w[t + 2], time_b[t + 2]));
            v.w = __cosf(fmaf(dt, time_w[t + 3], time_b[t + 3]));
        } else {
            v.x = v.y = v.z = v.w = 0.0f;
        }
        short4 s4;
        s4.x = f2bf(v.x); s4.y = f2bf(v.y); s4.z = f2bf(v.z); s4.w = f2bf(v.w);
        *reinterpret_cast<short4*>(&X[e][c]) = s4;
    }
    __syncthreads();

    const int w    = tid >> 6;
    const int l    = tid & 63;
    const int lrow = l & 15;
    const int lkg  = l >> 4;
    const int et   = w & 1;    // edge tile (16 edges)
    const int nh   = w >> 1;   // output half (64 outputs)

    f32x4 acc[4];
#pragma unroll
    for (int n = 0; n < 4; n++) acc[n] = (f32x4){0.f, 0.f, 0.f, 0.f};

#pragma unroll 4
    for (int s = 0; s < 16; ++s) {
        bf16x8 A = *reinterpret_cast<const bf16x8*>(&X[et * 16 + lrow][s * 32 + lkg * 8]);
#pragma unroll
        for (int ntl = 0; ntl < 4; ++ntl) {
            int t = nh * 4 + ntl;
            bf16x8 B = *reinterpret_cast<const bf16x8*>(&wfm[(size_t)(((t * 16 + s) * 64) + l) * 8]);
            acc[ntl] = __builtin_amdgcn_mfma_f32_16x16x32_bf16(A, B, acc[ntl], 0, 0, 0);
        }
    }

    // Epilogue: bias + f32 atomic scatter to both endpoints.
#pragma unroll
    for (int ntl = 0; ntl < 4; ++ntl) {
        int j = nh * 64 + ntl * 16 + lrow;
        float bias = msg_b[j];
#pragma unroll
        for (int r = 0; r < 4; ++r) {
            int el = et * 16 + lkg * 4 + r;
            float m = acc[ntl][r] + bias;
            atomicAdd(&sums[(size_t)sid[el] * 128 + j], m);
            atomicAdd(&sums[(size_t)did[el] * 128 + j], m);
        }
    }
}

// ---------------------------------------------------------------------------
// Kernel B: fused MFMA GEMM + GRU gates.  32 nodes/block, 256 threads.
// Wave w owns j-slice [w*32, w*32+32), all 4 gate quadrants, 2 node tiles.
// Reads f32 sums/counts from d_out, overwrites d_out in place.
// (round-4 structure with the proven f32 sums read)
// ---------------------------------------------------------------------------
#define GNT 32

__global__ __launch_bounds__(256, 3) void tgn_gru_mfma(
    const float* __restrict__ memory,
    const float* __restrict__ last_update,
    const float* __restrict__ timestamps,
    const float* __restrict__ b_ih,
    const float* __restrict__ b_hh,
    const short* __restrict__ wfrag,
    float* __restrict__ out)
{
    __shared__ short X[GNT][264];
    __shared__ float cntS[GNT];

    const int tid = threadIdx.x;
    const int n0 = blockIdx.x * GNT;
    const float* sums   = out;
    const float* counts = out + (size_t)N_NODES * 128;

    if (tid < GNT) cntS[tid] = counts[n0 + tid];
    __syncthreads();

    // Stage X = [agg | mem] as bf16
    for (int i = tid; i < GNT * 32; i += 256) {
        int m = i >> 5;
        int c = (i & 31) * 4;
        float inv = 1.0f / fmaxf(cntS[m], 1.0f);
        float4 v = *reinterpret_cast<const float4*>(&sums[(size_t)(n0 + m) * 128 + c]);
        short4 a4;
        a4.x = f2bf(v.x * inv); a4.y = f2bf(v.y * inv);
        a4.z = f2bf(v.z * inv); a4.w = f2bf(v.w * inv);
        *reinterpret_cast<short4*>(&X[m][c]) = a4;
        float4 mv = *reinterpret_cast<const float4*>(&memory[(size_t)(n0 + m) * 128 + c]);
        short4 m4;
        m4.x = f2bf(mv.x); m4.y = f2bf(mv.y); m4.z = f2bf(mv.z); m4.w = f2bf(mv.w);
        *reinterpret_cast<short4*>(&X[m][128 + c]) = m4;
    }
    __syncthreads();

    const int w    = tid >> 6;
    const int l    = tid & 63;
    const int lrow = l & 15;
    const int lkg  = l >> 4;

    f32x4 acc[4][2][2];   // [quadrant][jt][mt]
#pragma unroll
    for (int q = 0; q < 4; q++)
#pragma unroll
        for (int jt = 0; jt < 2; jt++)
#pragma unroll
            for (int mt = 0; mt < 2; mt++)
                acc[q][jt][mt] = (f32x4){0.f, 0.f, 0.f, 0.f};

    for (int s = 0; s < 8; ++s) {
        bf16x8 A[2];
#pragma unroll
        for (int mt = 0; mt < 2; ++mt)
            A[mt] = *reinterpret_cast<const bf16x8*>(&X[mt * 16 + lrow][s * 32 + lkg * 8]);
#pragma unroll
        for (int q = 0; q < 4; ++q)
#pragma unroll
            for (int jt = 0; jt < 2; ++jt) {
                int t = q * 8 + w * 2 + jt;
                bf16x8 B = *reinterpret_cast<const bf16x8*>(&wfrag[(size_t)(((t * 8 + s) * 64) + l) * 8]);
#pragma unroll
                for (int mt = 0; mt < 2; ++mt)
                    acc[q][jt][mt] = __builtin_amdgcn_mfma_f32_16x16x32_bf16(
                        A[mt], B, acc[q][jt][mt], 0, 0, 0);
            }
    }

    const float ts0 = timestamps[0];

#pragma unroll
    for (int jt = 0; jt < 2; ++jt) {
        int j = w * 32 + jt * 16 + lrow;
        float br  = b_ih[j]       + b_hh[j];
        float bz  = b_ih[128 + j] + b_hh[128 + j];
        float bin = b_ih[256 + j];
        float bhn = b_hh[256 + j];
#pragma unroll
        for (int mt = 0; mt < 2; ++mt) {
#pragma unroll
            for (int r = 0; r < 4; ++r) {
                int mloc = mt * 16 + lkg * 4 + r;
                int node = n0 + mloc;
                float rg  = acc[0][jt][mt][r] + br;
                float zg  = acc[1][jt][mt][r] + bz;
                float ing = acc[2][jt][mt][r] + bin;
                float hng = acc[3][jt][mt][r] + bhn;
                float rr = fsigmoid(rg);
                float zz = fsigmoid(zg);
                float nn = ftanh(ing + rr * hng);
                float mv = memory[(size_t)node * 128 + j];
                float h  = (1.0f - zz) * nn + zz * mv;
                out[(size_t)node * 128 + j] = (cntS[mloc] > 0.0f) ? h : mv;
            }
        }
    }

    if (tid < GNT) {
        int node = n0 + tid;
        out[(size_t)N_NODES * 128 + node] = (cntS[tid] > 0.0f) ? ts0 : last_update[node];
    }
}

// ---------------------------------------------------------------------------
extern "C" void kernel_launch(void* const* d_in, const int* in_sizes, int n_in,
                              void* d_out, int out_size, void* d_ws, size_t ws_size,
                              hipStream_t stream) {
    const float* memory        = (const float*)d_in[0];
    const float* last_update   = (const float*)d_in[1];
    const float* timestamps    = (const float*)d_in[2];
    const float* edge_features = (const float*)d_in[3];
    const float* msg_W         = (const float*)d_in[4];
    const float* msg_b         = (const float*)d_in[5];
    const float* gru_W_ih      = (const float*)d_in[6];
    const float* gru_W_hh      = (const float*)d_in[7];
    const float* gru_b_ih      = (const float*)d_in[8];
    const float* gru_b_hh      = (const float*)d_in[9];
    const float* time_w        = (const float*)d_in[10];
    const float* time_b        = (const float*)d_in[11];
    const int*   src           = (const int*)d_in[12];
    const int*   dst           = (const int*)d_in[13];

    float* out = (float*)d_out;
    short* wfrag_gru = (short*)d_ws;            // 131072 bf16 = 256 KB
    short* wfrag_msg = (short*)d_ws + 131072;   //  65536 bf16 = 128 KB

    // sums/counts accumulators live in d_out (round-3 proven layout)
    hipMemsetAsync(d_out, 0, (size_t)out_size * sizeof(float), stream);

    float* sums   = out;
    float* counts = out + (size_t)N_NODES * 128;

    tgn_prep_wgru<<<512, 256, 0, stream>>>(gru_W_ih, gru_W_hh, wfrag_gru);
    tgn_prep_wmsg<<<256, 256, 0, stream>>>(msg_W, wfrag_msg);

    tgn_msg_mfma<<<E_EDGES / TE, 256, 0, stream>>>(
        memory, last_update, timestamps, edge_features, msg_b,
        time_w, time_b, src, dst, wfrag_msg, sums, counts);

    tgn_gru_mfma<<<N_NODES / GNT, 256, 0, stream>>>(
        memory, last_update, timestamps, gru_b_ih, gru_b_hh, wfrag_gru, out);
}

// Round 9
// 253.534 us; speedup vs baseline: 1.4337x; 1.3127x over previous
//
#include <hip/hip_runtime.h>
#include <math.h>

#define N_NODES 200000
#define E_EDGES 100000
#define TIME_DIM 100
#define RAW_DIM 484   // 128 + 128 + 128 + 100
#define CAP 10        // per-node direct slots (Poisson(1): P(deg>10) ~ 1e-8)
#define OVF_MAX 8192

typedef short  bf16x8 __attribute__((ext_vector_type(8)));
typedef float  f32x4  __attribute__((ext_vector_type(4)));
typedef unsigned int uint;

__device__ __forceinline__ short f2bf(float f) {
    unsigned u = __builtin_bit_cast(unsigned, f);
    u = (u + 0x7FFFu + ((u >> 16) & 1u)) >> 16;   // RNE
    return (short)u;
}
__device__ __forceinline__ float fsigmoid(float x) {
    return __builtin_amdgcn_rcpf(1.0f + __expf(-x));
}
__device__ __forceinline__ float ftanh(float x) {
    float t = __expf(2.0f * x);
    return 1.0f - 2.0f * __builtin_amdgcn_rcpf(t + 1.0f);
}
// pack 8 consecutive f32 -> 8 consecutive bf16 (RNE via v_cvt_pk_bf16_f32)
__device__ __forceinline__ bf16x8 pack8(float4 a, float4 b) {
    unsigned r0, r1, r2, r3;
    asm("v_cvt_pk_bf16_f32 %0, %1, %2" : "=v"(r0) : "v"(a.x), "v"(a.y));
    asm("v_cvt_pk_bf16_f32 %0, %1, %2" : "=v"(r1) : "v"(a.z), "v"(a.w));
    asm("v_cvt_pk_bf16_f32 %0, %1, %2" : "=v"(r2) : "v"(b.x), "v"(b.y));
    asm("v_cvt_pk_bf16_f32 %0, %1, %2" : "=v"(r3) : "v"(b.z), "v"(b.w));
    uint4 u = {r0, r1, r2, r3};
    return __builtin_bit_cast(bf16x8, u);
}

// ---------------------------------------------------------------------------
// Prep 1: pack msg_W [128][484] -> bf16 B-fragment order, K padded to 512.
// ---------------------------------------------------------------------------
__global__ __launch_bounds__(256) void tgn_prep_wmsg(
    const float* __restrict__ msgW, short* __restrict__ wf)
{
    int idx = blockIdx.x * 256 + threadIdx.x;   // 0 .. 65535
    int j = idx & 7;
    int l = (idx >> 3) & 63;
    int s = (idx >> 9) & 15;
    int t = idx >> 13;
    int n = t * 16 + (l & 15);
    int k = s * 32 + (l >> 4) * 8 + j;
    float v = (k < RAW_DIM) ? msgW[(size_t)n * RAW_DIM + k] : 0.0f;
    wf[idx] = f2bf(v);
}

// ---------------------------------------------------------------------------
// Prep 2: pack combined GRU weight matrix W_big[512][256] into B-frag order.
// ---------------------------------------------------------------------------
__global__ __launch_bounds__(256) void tgn_prep_wgru(
    const float* __restrict__ Wih, const float* __restrict__ Whh,
    short* __restrict__ wf)
{
    int idx = blockIdx.x * 256 + threadIdx.x;   // 0 .. 131071
    int j = idx & 7;
    int l = (idx >> 3) & 63;
    int s = (idx >> 9) & 7;
    int t = idx >> 12;
    int n = t * 16 + (l & 15);
    int k = s * 32 + (l >> 4) * 8 + j;
    int half = k >> 7;
    int kk = k & 127;
    float v;
    if (n < 256) {
        v = half ? Whh[(size_t)n * 128 + kk] : Wih[(size_t)n * 128 + kk];
    } else if (n < 384) {
        v = half ? 0.0f : Wih[(size_t)n * 128 + kk];
    } else {
        v = half ? Whh[(size_t)(n - 128) * 128 + kk] : 0.0f;
    }
    wf[idx] = f2bf(v);
}

// ---------------------------------------------------------------------------
// Tickets: one thread per edge; u32 rank atomics build per-node slot lists.
// ---------------------------------------------------------------------------
__global__ __launch_bounds__(256) void tgn_tickets(
    const int* __restrict__ src, const int* __restrict__ dst,
    uint* __restrict__ idxv, uint* __restrict__ cnt, uint* __restrict__ ovf)
{
    int i = blockIdx.x * 256 + threadIdx.x;
    if (i >= E_EDGES) return;
    int s = src[i];
    int d = dst[i];
    uint rs = atomicAdd(&cnt[s], 1u);
    if (rs < CAP) {
        idxv[(size_t)s * CAP + rs] = (uint)i;
    } else {
        uint o = atomicAdd(&ovf[0], 1u);
        if (o < OVF_MAX) { ovf[1 + 2 * o] = (uint)s; ovf[2 + 2 * o] = (uint)i; }
    }
    uint rd = atomicAdd(&cnt[d], 1u);
    if (rd < CAP) {
        idxv[(size_t)d * CAP + rd] = (uint)i;
    } else {
        uint o = atomicAdd(&ovf[0], 1u);
        if (o < OVF_MAX) { ovf[1 + 2 * o] = (uint)d; ovf[2 + 2 * o] = (uint)i; }
    }
}

// ---------------------------------------------------------------------------
// Kernel A (f32 store): register-gather MFMA message MLP, NO atomics.
// 128 threads = 2 waves; wave owns 16 edges x all 128 outputs.
// Epilogue: each lane stores its own C elements as f32 (linear rows).
// ---------------------------------------------------------------------------
#define MTE 32

__global__ __launch_bounds__(128, 2) void tgn_msg_f32(
    const float* __restrict__ memory,
    const float* __restrict__ last_update,
    const float* __restrict__ timestamps,
    const float* __restrict__ edge_features,
    const float* __restrict__ msg_b,
    const float* __restrict__ time_w,
    const float* __restrict__ time_b,
    const int*   __restrict__ src,
    const int*   __restrict__ dst,
    const short* __restrict__ wfm,
    float* __restrict__ msgf)
{
    const int tid  = threadIdx.x;
    const int wv   = tid >> 6;
    const int l    = tid & 63;
    const int lrow = l & 15;
    const int lkg  = l >> 4;
    const int e0   = blockIdx.x * MTE + wv * 16;
    const int e    = e0 + lrow;

    const int sid = src[e];
    const int did = dst[e];
    const float dt = timestamps[e] - last_update[sid];

    // ---- issue all gathers (24 independent dwordx4 per lane) ----
    const float* srcm = memory        + (size_t)sid * 128 + lkg * 8;
    const float* dstm = memory        + (size_t)did * 128 + lkg * 8;
    const float* ef   = edge_features + (size_t)e   * 128 + lkg * 8;
    float4 bufS[8], bufD[8], bufE[8];
#pragma unroll
    for (int s = 0; s < 4; ++s) {
        bufS[2 * s]     = *reinterpret_cast<const float4*>(srcm + s * 32);
        bufS[2 * s + 1] = *reinterpret_cast<const float4*>(srcm + s * 32 + 4);
        bufD[2 * s]     = *reinterpret_cast<const float4*>(dstm + s * 32);
        bufD[2 * s + 1] = *reinterpret_cast<const float4*>(dstm + s * 32 + 4);
        bufE[2 * s]     = *reinterpret_cast<const float4*>(ef + s * 32);
        bufE[2 * s + 1] = *reinterpret_cast<const float4*>(ef + s * 32 + 4);
    }

    // ---- time-encoding chunks on VALU while loads are in flight ----
    bf16x8 afr[16];
#pragma unroll
    for (int s = 12; s < 16; ++s) {
        int k0 = s * 32 + lkg * 8;
        float4 lo, hi;
#pragma unroll
        for (int j = 0; j < 8; ++j) {
            int k = k0 + j;
            float v = 0.0f;
            if (k < RAW_DIM) {
                int t = k - 384;
                v = __cosf(fmaf(dt, time_w[t], time_b[t]));
            }
            if (j < 4) (&lo.x)[j] = v; else (&hi.x)[j - 4] = v;
        }
        afr[s] = pack8(lo, hi);
    }

#pragma unroll
    for (int s = 0; s < 4; ++s) {
        afr[s]     = pack8(bufS[2 * s], bufS[2 * s + 1]);
        afr[4 + s] = pack8(bufD[2 * s], bufD[2 * s + 1]);
        afr[8 + s] = pack8(bufE[2 * s], bufE[2 * s + 1]);
    }

    // ---- MFMA: 16 k-steps x 8 output tiles ----
    f32x4 acc[8];
#pragma unroll
    for (int t = 0; t < 8; ++t) acc[t] = (f32x4){0.f, 0.f, 0.f, 0.f};

#pragma unroll
    for (int s = 0; s < 16; ++s) {
#pragma unroll
        for (int t = 0; t < 8; ++t) {
            bf16x8 B = *reinterpret_cast<const bf16x8*>(
                &wfm[(size_t)(((t * 16 + s) * 64) + l) * 8]);
            acc[t] = __builtin_amdgcn_mfma_f32_16x16x32_bf16(afr[s], B, acc[t], 0, 0, 0);
        }
    }

    // ---- epilogue: bias + plain f32 stores (each lane its own elements) ----
#pragma unroll
    for (int r = 0; r < 4; ++r) {
        int erow = e0 + lkg * 4 + r;                  // C row = global edge id
        float* orow = msgf + (size_t)erow * 128;
#pragma unroll
        for (int t = 0; t < 8; ++t) {
            int j = t * 16 + lrow;                    // C col = output dim
            orow[j] = acc[t][r] + msg_b[j];
        }
    }
}

// ---------------------------------------------------------------------------
// Kernel B (f32 gather): per-node gather of <=CAP message rows (+ overflow),
// f32 mean, then proven MFMA GRU.  32 nodes/block, 256 threads.
// ---------------------------------------------------------------------------
#define GNT 32

__global__ __launch_bounds__(256, 3) void tgn_gru_f32(
    const float* __restrict__ memory,
    const float* __restrict__ last_update,
    const float* __restrict__ timestamps,
    const float* __restrict__ b_ih,
    const float* __restrict__ b_hh,
    const short* __restrict__ wfrag,
    const float* __restrict__ msgf,
    const uint*  __restrict__ idxv,
    const uint*  __restrict__ cnt,
    const uint*  __restrict__ ovf,
    float* __restrict__ out)
{
    __shared__ short X[GNT][264];
    __shared__ float cntS[GNT];

    const int tid = threadIdx.x;
    const int n0 = blockIdx.x * GNT;

    // gather-aggregate agg -> X[:, 0:128]; 8 threads/node, 16 dims each
    {
        int nloc = tid >> 3;
        int p    = tid & 7;
        int node = n0 + nloc;
        uint c = cnt[node];
        if (p == 0) cntS[nloc] = (float)c;
        float a[16];
#pragma unroll
        for (int q = 0; q < 16; ++q) a[q] = 0.0f;
        uint cm = (c < CAP) ? c : (uint)CAP;
        for (uint i = 0; i < cm; ++i) {
            uint eid = idxv[(size_t)node * CAP + i];
            const float* row = msgf + (size_t)eid * 128 + p * 16;
            float4 v0 = *reinterpret_cast<const float4*>(row);
            float4 v1 = *reinterpret_cast<const float4*>(row + 4);
            float4 v2 = *reinterpret_cast<const float4*>(row + 8);
            float4 v3 = *reinterpret_cast<const float4*>(row + 12);
            a[0] += v0.x;  a[1] += v0.y;  a[2]  += v0.z;  a[3]  += v0.w;
            a[4] += v1.x;  a[5] += v1.y;  a[6]  += v1.z;  a[7]  += v1.w;
            a[8] += v2.x;  a[9] += v2.y;  a[10] += v2.z;  a[11] += v2.w;
            a[12] += v3.x; a[13] += v3.y; a[14] += v3.z;  a[15] += v3.w;
        }
        if (c > CAP) {                       // rare: scan overflow list
            uint L = ovf[0];
            if (L > OVF_MAX) L = OVF_MAX;
            for (uint i = 0; i < L; ++i) {
                if (ovf[1 + 2 * i] == (uint)node) {
                    uint eid = ovf[2 + 2 * i];
                    const float* row = msgf + (size_t)eid * 128 + p * 16;
                    float4 v0 = *reinterpret_cast<const float4*>(row);
                    float4 v1 = *reinterpret_cast<const float4*>(row + 4);
                    float4 v2 = *reinterpret_cast<const float4*>(row + 8);
                    float4 v3 = *reinterpret_cast<const float4*>(row + 12);
                    a[0] += v0.x;  a[1] += v0.y;  a[2]  += v0.z;  a[3]  += v0.w;
                    a[4] += v1.x;  a[5] += v1.y;  a[6]  += v1.z;  a[7]  += v1.w;
                    a[8] += v2.x;  a[9] += v2.y;  a[10] += v2.z;  a[11] += v2.w;
                    a[12] += v3.x; a[13] += v3.y; a[14] += v3.z;  a[15] += v3.w;
                }
            }
        }
        float inv = (c > 0) ? (1.0f / (float)c) : 0.0f;
#pragma unroll
        for (int q = 0; q < 16; ++q) a[q] *= inv;
        short4 o0 = { f2bf(a[0]),  f2bf(a[1]),  f2bf(a[2]),  f2bf(a[3])  };
        short4 o1 = { f2bf(a[4]),  f2bf(a[5]),  f2bf(a[6]),  f2bf(a[7])  };
        short4 o2 = { f2bf(a[8]),  f2bf(a[9]),  f2bf(a[10]), f2bf(a[11]) };
        short4 o3 = { f2bf(a[12]), f2bf(a[13]), f2bf(a[14]), f2bf(a[15]) };
        *reinterpret_cast<short4*>(&X[nloc][p * 16 + 0])  = o0;
        *reinterpret_cast<short4*>(&X[nloc][p * 16 + 4])  = o1;
        *reinterpret_cast<short4*>(&X[nloc][p * 16 + 8])  = o2;
        *reinterpret_cast<short4*>(&X[nloc][p * 16 + 12]) = o3;
    }

    // stage memory -> X[:, 128:256]
    for (int i = tid; i < GNT * 32; i += 256) {
        int m = i >> 5;
        int c4 = (i & 31) * 4;
        float4 mv = *reinterpret_cast<const float4*>(&memory[(size_t)(n0 + m) * 128 + c4]);
        short4 m4;
        m4.x = f2bf(mv.x); m4.y = f2bf(mv.y); m4.z = f2bf(mv.z); m4.w = f2bf(mv.w);
        *reinterpret_cast<short4*>(&X[m][128 + c4]) = m4;
    }
    __syncthreads();

    const int w    = tid >> 6;
    const int l    = tid & 63;
    const int lrow = l & 15;
    const int lkg  = l >> 4;

    f32x4 acc[4][2][2];   // [quadrant][jt][mt]
#pragma unroll
    for (int q = 0; q < 4; q++)
#pragma unroll
        for (int jt = 0; jt < 2; jt++)
#pragma unroll
            for (int mt = 0; mt < 2; mt++)
                acc[q][jt][mt] = (f32x4){0.f, 0.f, 0.f, 0.f};

    for (int s = 0; s < 8; ++s) {
        bf16x8 A[2];
#pragma unroll
        for (int mt = 0; mt < 2; ++mt)
            A[mt] = *reinterpret_cast<const bf16x8*>(&X[mt * 16 + lrow][s * 32 + lkg * 8]);
#pragma unroll
        for (int q = 0; q < 4; ++q)
#pragma unroll
            for (int jt = 0; jt < 2; ++jt) {
                int t = q * 8 + w * 2 + jt;
                bf16x8 B = *reinterpret_cast<const bf16x8*>(&wfrag[(size_t)(((t * 8 + s) * 64) + l) * 8]);
#pragma unroll
                for (int mt = 0; mt < 2; ++mt)
                    acc[q][jt][mt] = __builtin_amdgcn_mfma_f32_16x16x32_bf16(
                        A[mt], B, acc[q][jt][mt], 0, 0, 0);
            }
    }

    const float ts0 = timestamps[0];

#pragma unroll
    for (int jt = 0; jt < 2; ++jt) {
        int j = w * 32 + jt * 16 + lrow;
        float br  = b_ih[j]       + b_hh[j];
        float bz  = b_ih[128 + j] + b_hh[128 + j];
        float bin = b_ih[256 + j];
        float bhn = b_hh[256 + j];
#pragma unroll
        for (int mt = 0; mt < 2; ++mt) {
#pragma unroll
            for (int r = 0; r < 4; ++r) {
                int mloc = mt * 16 + lkg * 4 + r;
                int node = n0 + mloc;
                float rg  = acc[0][jt][mt][r] + br;
                float zg  = acc[1][jt][mt][r] + bz;
                float ing = acc[2][jt][mt][r] + bin;
                float hng = acc[3][jt][mt][r] + bhn;
                float rr = fsigmoid(rg);
                float zz = fsigmoid(zg);
                float nn = ftanh(ing + rr * hng);
                float mv = memory[(size_t)node * 128 + j];
                float h  = (1.0f - zz) * nn + zz * mv;
                out[(size_t)node * 128 + j] = (cntS[mloc] > 0.0f) ? h : mv;
            }
        }
    }

    if (tid < GNT) {
        int node = n0 + tid;
        out[(size_t)N_NODES * 128 + node] = (cntS[tid] > 0.0f) ? ts0 : last_update[node];
    }
}

// ---------------------------------------------------------------------------
// Fallback kernels (f32 atomics via d_out) — round-7 proven, used if ws too
// small for the f32-CSR path.
// ---------------------------------------------------------------------------
#define TE 32

__global__ __launch_bounds__(256, 2) void tgn_msg_mfma(
    const float* __restrict__ memory,
    const float* __restrict__ last_update,
    const float* __restrict__ timestamps,
    const float* __restrict__ edge_features,
    const float* __restrict__ msg_b,
    const float* __restrict__ time_w,
    const float* __restrict__ time_b,
    const int*   __restrict__ src,
    const int*   __restrict__ dst,
    const short* __restrict__ wfm,
    float* __restrict__ sums,
    float* __restrict__ counts)
{
    __shared__ short X[TE][520];
    __shared__ int   sid[TE];
    __shared__ int   did[TE];
    __shared__ float dtS[TE];

    const int tid = threadIdx.x;
    const int e0  = blockIdx.x * TE;

    if (tid < TE) {
        int s = src[e0 + tid];
        int d = dst[e0 + tid];
        sid[tid] = s;
        did[tid] = d;
        dtS[tid] = timestamps[e0 + tid] - last_update[s];
        atomicAdd(&counts[s], 1.0f);
        atomicAdd(&counts[d], 1.0f);
    }
    __syncthreads();

    for (int i = tid; i < TE * 128; i += 256) {
        int e = i >> 7;
        int c = (i & 127) * 4;
        float4 v;
        if (c < 128) {
            v = *reinterpret_cast<const float4*>(&memory[(size_t)sid[e] * 128 + c]);
        } else if (c < 256) {
            v = *reinterpret_cast<const float4*>(&memory[(size_t)did[e] * 128 + (c - 128)]);
        } else if (c < 384) {
            v = *reinterpret_cast<const float4*>(&edge_features[(size_t)(e0 + e) * 128 + (c - 256)]);
        } else if (c < 484) {
            float dt = dtS[e];
            int t = c - 384;
            v.x = __cosf(fmaf(dt, time_w[t + 0], time_b[t + 0]));
            v.y = __cosf(fmaf(dt, time_w[t + 1], time_b[t + 1]));
            v.z = __cosf(fmaf(dt, time_w[t + 2], time_b[t + 2]));
            v.w = __cosf(fmaf(dt, time_w[t + 3], time_b[t + 3]));
        } else {
            v.x = v.y = v.z = v.w = 0.0f;
        }
        short4 s4;
        s4.x = f2bf(v.x); s4.y = f2bf(v.y); s4.z = f2bf(v.z); s4.w = f2bf(v.w);
        *reinterpret_cast<short4*>(&X[e][c]) = s4;
    }
    __syncthreads();

    const int w    = tid >> 6;
    const int l    = tid & 63;
    const int lrow = l & 15;
    const int lkg  = l >> 4;
    const int et   = w & 1;
    const int nh   = w >> 1;

    f32x4 acc[4];
#pragma unroll
    for (int n = 0; n < 4; n++) acc[n] = (f32x4){0.f, 0.f, 0.f, 0.f};

#pragma unroll 4
    for (int s = 0; s < 16; ++s) {
        bf16x8 A = *reinterpret_cast<const bf16x8*>(&X[et * 16 + lrow][s * 32 + lkg * 8]);
#pragma unroll
        for (int ntl = 0; ntl < 4; ++ntl) {
            int t = nh * 4 + ntl;
            bf16x8 B = *reinterpret_cast<const bf16x8*>(&wfm[(size_t)(((t * 16 + s) * 64) + l) * 8]);
            acc[ntl] = __builtin_amdgcn_mfma_f32_16x16x32_bf16(A, B, acc[ntl], 0, 0, 0);
        }
    }

#pragma unroll
    for (int ntl = 0; ntl < 4; ++ntl) {
        int j = nh * 64 + ntl * 16 + lrow;
        float bias = msg_b[j];
#pragma unroll
        for (int r = 0; r < 4; ++r) {
            int el = et * 16 + lkg * 4 + r;
            float m = acc[ntl][r] + bias;
            atomicAdd(&sums[(size_t)sid[el] * 128 + j], m);
            atomicAdd(&sums[(size_t)did[el] * 128 + j], m);
        }
    }
}

__global__ __launch_bounds__(256, 3) void tgn_gru_mfma(
    const float* __restrict__ memory,
    const float* __restrict__ last_update,
    const float* __restrict__ timestamps,
    const float* __restrict__ b_ih,
    const float* __restrict__ b_hh,
    const short* __restrict__ wfrag,
    float* __restrict__ out)
{
    __shared__ short X[GNT][264];
    __shared__ float cntS[GNT];

    const int tid = threadIdx.x;
    const int n0 = blockIdx.x * GNT;
    const float* sums   = out;
    const float* counts = out + (size_t)N_NODES * 128;

    if (tid < GNT) cntS[tid] = counts[n0 + tid];
    __syncthreads();

    for (int i = tid; i < GNT * 32; i += 256) {
        int m = i >> 5;
        int c = (i & 31) * 4;
        float inv = 1.0f / fmaxf(cntS[m], 1.0f);
        float4 v = *reinterpret_cast<const float4*>(&sums[(size_t)(n0 + m) * 128 + c]);
        short4 a4;
        a4.x = f2bf(v.x * inv); a4.y = f2bf(v.y * inv);
        a4.z = f2bf(v.z * inv); a4.w = f2bf(v.w * inv);
        *reinterpret_cast<short4*>(&X[m][c]) = a4;
        float4 mv = *reinterpret_cast<const float4*>(&memory[(size_t)(n0 + m) * 128 + c]);
        short4 m4;
        m4.x = f2bf(mv.x); m4.y = f2bf(mv.y); m4.z = f2bf(mv.z); m4.w = f2bf(mv.w);
        *reinterpret_cast<short4*>(&X[m][128 + c]) = m4;
    }
    __syncthreads();

    const int w    = tid >> 6;
    const int l    = tid & 63;
    const int lrow = l & 15;
    const int lkg  = l >> 4;

    f32x4 acc[4][2][2];
#pragma unroll
    for (int q = 0; q < 4; q++)
#pragma unroll
        for (int jt = 0; jt < 2; jt++)
#pragma unroll
            for (int mt = 0; mt < 2; mt++)
                acc[q][jt][mt] = (f32x4){0.f, 0.f, 0.f, 0.f};

    for (int s = 0; s < 8; ++s) {
        bf16x8 A[2];
#pragma unroll
        for (int mt = 0; mt < 2; ++mt)
            A[mt] = *reinterpret_cast<const bf16x8*>(&X[mt * 16 + lrow][s * 32 + lkg * 8]);
#pragma unroll
        for (int q = 0; q < 4; ++q)
#pragma unroll
            for (int jt = 0; jt < 2; ++jt) {
                int t = q * 8 + w * 2 + jt;
                bf16x8 B = *reinterpret_cast<const bf16x8*>(&wfrag[(size_t)(((t * 8 + s) * 64) + l) * 8]);
#pragma unroll
                for (int mt = 0; mt < 2; ++mt)
                    acc[q][jt][mt] = __builtin_amdgcn_mfma_f32_16x16x32_bf16(
                        A[mt], B, acc[q][jt][mt], 0, 0, 0);
            }
    }

    const float ts0 = timestamps[0];
#pragma unroll
    for (int jt = 0; jt < 2; ++jt) {
        int j = w * 32 + jt * 16 + lrow;
        float br  = b_ih[j]       + b_hh[j];
        float bz  = b_ih[128 + j] + b_hh[128 + j];
        float bin = b_ih[256 + j];
        float bhn = b_hh[256 + j];
#pragma unroll
        for (int mt = 0; mt < 2; ++mt) {
#pragma unroll
            for (int r = 0; r < 4; ++r) {
                int mloc = mt * 16 + lkg * 4 + r;
                int node = n0 + mloc;
                float rg  = acc[0][jt][mt][r] + br;
                float zg  = acc[1][jt][mt][r] + bz;
                float ing = acc[2][jt][mt][r] + bin;
                float hng = acc[3][jt][mt][r] + bhn;
                float rr = fsigmoid(rg);
                float zz = fsigmoid(zg);
                float nn = ftanh(ing + rr * hng);
                float mv = memory[(size_t)node * 128 + j];
                float h  = (1.0f - zz) * nn + zz * mv;
                out[(size_t)node * 128 + j] = (cntS[mloc] > 0.0f) ? h : mv;
            }
        }
    }
    if (tid < GNT) {
        int node = n0 + tid;
        out[(size_t)N_NODES * 128 + node] = (cntS[tid] > 0.0f) ? ts0 : last_update[node];
    }
}

// ---------------------------------------------------------------------------
extern "C" void kernel_launch(void* const* d_in, const int* in_sizes, int n_in,
                              void* d_out, int out_size, void* d_ws, size_t ws_size,
                              hipStream_t stream) {
    const float* memory        = (const float*)d_in[0];
    const float* last_update   = (const float*)d_in[1];
    const float* timestamps    = (const float*)d_in[2];
    const float* edge_features = (const float*)d_in[3];
    const float* msg_W         = (const float*)d_in[4];
    const float* msg_b         = (const float*)d_in[5];
    const float* gru_W_ih      = (const float*)d_in[6];
    const float* gru_W_hh      = (const float*)d_in[7];
    const float* gru_b_ih      = (const float*)d_in[8];
    const float* gru_b_hh      = (const float*)d_in[9];
    const float* time_w        = (const float*)d_in[10];
    const float* time_b        = (const float*)d_in[11];
    const int*   src           = (const int*)d_in[12];
    const int*   dst           = (const int*)d_in[13];

    float* out = (float*)d_out;
    char* ws = (char*)d_ws;

    const size_t OFF_WGRU = 0;                                   // 256 KB
    const size_t OFF_WMSG = 262144;                              // 128 KB
    const size_t OFF_MSGF = 393216;                              // E*128 f32
    const size_t SZ_MSGF  = (size_t)E_EDGES * 128 * 4;           // 51.2 MB
    const size_t OFF_IDX  = OFF_MSGF + SZ_MSGF;                  // N*CAP u32
    const size_t SZ_IDX   = (size_t)N_NODES * CAP * 4;           // 8 MB
    const size_t OFF_CNT  = OFF_IDX + SZ_IDX;                    // N u32
    const size_t OFF_OVF  = OFF_CNT + (size_t)N_NODES * 4;
    const size_t WS_NEED  = OFF_OVF + 4 + (size_t)OVF_MAX * 8;

    short* wfrag_gru = (short*)(ws + OFF_WGRU);
    short* wfrag_msg = (short*)(ws + OFF_WMSG);

    tgn_prep_wgru<<<512, 256, 0, stream>>>(gru_W_ih, gru_W_hh, wfrag_gru);
    tgn_prep_wmsg<<<256, 256, 0, stream>>>(msg_W, wfrag_msg);

    if (ws_size >= WS_NEED) {
        float* msgf = (float*)(ws + OFF_MSGF);
        uint*  idxv = (uint*)(ws + OFF_IDX);
        uint*  cnt  = (uint*)(ws + OFF_CNT);
        uint*  ovf  = (uint*)(ws + OFF_OVF);

        // zero cnt + ovf counter only (contiguous, ~800 KB)
        hipMemsetAsync(ws + OFF_CNT, 0, (size_t)N_NODES * 4 + 16, stream);

        tgn_tickets<<<(E_EDGES + 255) / 256, 256, 0, stream>>>(src, dst, idxv, cnt, ovf);

        tgn_msg_f32<<<E_EDGES / MTE, 128, 0, stream>>>(
            memory, last_update, timestamps, edge_features, msg_b,
            time_w, time_b, src, dst, wfrag_msg, msgf);

        tgn_gru_f32<<<N_NODES / GNT, 256, 0, stream>>>(
            memory, last_update, timestamps, gru_b_ih, gru_b_hh, wfrag_gru,
            msgf, idxv, cnt, ovf, out);
    } else {
        hipMemsetAsync(d_out, 0, (size_t)out_size * sizeof(float), stream);
        float* sums   = out;
        float* counts = out + (size_t)N_NODES * 128;

        tgn_msg_mfma<<<E_EDGES / TE, 256, 0, stream>>>(
            memory, last_update, timestamps, edge_features, msg_b,
            time_w, time_b, src, dst, wfrag_msg, sums, counts);

        tgn_gru_mfma<<<N_NODES / GNT, 256, 0, stream>>>(
            memory, last_update, timestamps, gru_b_ih, gru_b_hh, wfrag_gru, out);
    }
}

// Round 10
// 242.699 us; speedup vs baseline: 1.4977x; 1.0446x over previous
//
#include <hip/hip_runtime.h>
#include <math.h>

#define N_NODES 200000
#define E_EDGES 100000
#define TIME_DIM 100
#define RAW_DIM 484   // 128 + 128 + 128 + 100
#define CAP 10        // per-node direct slots (Poisson(1): P(deg>10) ~ 1e-8)
#define OVF_MAX 8192

typedef short  bf16x8 __attribute__((ext_vector_type(8)));
typedef float  f32x4  __attribute__((ext_vector_type(4)));
typedef unsigned int uint;

__device__ __forceinline__ short f2bf(float f) {
    unsigned u = __builtin_bit_cast(unsigned, f);
    u = (u + 0x7FFFu + ((u >> 16) & 1u)) >> 16;   // RNE
    return (short)u;
}
__device__ __forceinline__ float bf2f(unsigned short u) {
    return __builtin_bit_cast(float, ((unsigned)u) << 16);
}
__device__ __forceinline__ float fsigmoid(float x) {
    return __builtin_amdgcn_rcpf(1.0f + __expf(-x));
}
__device__ __forceinline__ float ftanh(float x) {
    float t = __expf(2.0f * x);
    return 1.0f - 2.0f * __builtin_amdgcn_rcpf(t + 1.0f);
}
// pack 2 f32 -> u32 of 2 bf16 (HW RNE)
__device__ __forceinline__ unsigned cvtpk(float a, float b) {
    unsigned r;
    asm("v_cvt_pk_bf16_f32 %0, %1, %2" : "=v"(r) : "v"(a), "v"(b));
    return r;
}
// pack 8 consecutive f32 -> 8 consecutive bf16
__device__ __forceinline__ bf16x8 pack8(float4 a, float4 b) {
    uint4 u = {cvtpk(a.x, a.y), cvtpk(a.z, a.w), cvtpk(b.x, b.y), cvtpk(b.z, b.w)};
    return __builtin_bit_cast(bf16x8, u);
}

// ---------------------------------------------------------------------------
// Setup (main path): prep both weight fragments + ticket slot lists, fused.
//   blocks [0,512)    : pack W_big[512][256] (GRU) -> wfg
//   blocks [512,768)  : pack msg_W -> wfm (K padded to 512)
//   blocks [768,1159) : tickets (cnt must be pre-zeroed)
// ---------------------------------------------------------------------------
__global__ __launch_bounds__(256) void tgn_setup(
    const float* __restrict__ Wih, const float* __restrict__ Whh,
    short* __restrict__ wfg,
    const float* __restrict__ msgW, short* __restrict__ wfm,
    const int* __restrict__ src, const int* __restrict__ dst,
    uint* __restrict__ idxv, uint* __restrict__ cnt, uint* __restrict__ ovf)
{
    int b = blockIdx.x;
    int tid = threadIdx.x;
    if (b < 512) {
        int idx = b * 256 + tid;                 // 0 .. 131071
        int j = idx & 7;
        int l = (idx >> 3) & 63;
        int s = (idx >> 9) & 7;
        int t = idx >> 12;
        int n = t * 16 + (l & 15);
        int k = s * 32 + (l >> 4) * 8 + j;
        int half = k >> 7;
        int kk = k & 127;
        float v;
        if (n < 256) {
            v = half ? Whh[(size_t)n * 128 + kk] : Wih[(size_t)n * 128 + kk];
        } else if (n < 384) {
            v = half ? 0.0f : Wih[(size_t)n * 128 + kk];
        } else {
            v = half ? Whh[(size_t)(n - 128) * 128 + kk] : 0.0f;
        }
        wfg[idx] = f2bf(v);
    } else if (b < 768) {
        int idx = (b - 512) * 256 + tid;         // 0 .. 65535
        int j = idx & 7;
        int l = (idx >> 3) & 63;
        int s = (idx >> 9) & 15;
        int t = idx >> 13;
        int n = t * 16 + (l & 15);
        int k = s * 32 + (l >> 4) * 8 + j;
        float v = (k < RAW_DIM) ? msgW[(size_t)n * RAW_DIM + k] : 0.0f;
        wfm[idx] = f2bf(v);
    } else {
        int i = (b - 768) * 256 + tid;
        if (i < E_EDGES) {
            int s = src[i];
            int d = dst[i];
            uint rs = atomicAdd(&cnt[s], 1u);
            if (rs < CAP) {
                idxv[(size_t)s * CAP + rs] = (uint)i;
            } else {
                uint o = atomicAdd(&ovf[0], 1u);
                if (o < OVF_MAX) { ovf[1 + 2 * o] = (uint)s; ovf[2 + 2 * o] = (uint)i; }
            }
            uint rd = atomicAdd(&cnt[d], 1u);
            if (rd < CAP) {
                idxv[(size_t)d * CAP + rd] = (uint)i;
            } else {
                uint o = atomicAdd(&ovf[0], 1u);
                if (o < OVF_MAX) { ovf[1 + 2 * o] = (uint)d; ovf[2 + 2 * o] = (uint)i; }
            }
        }
    }
}

// ---------------------------------------------------------------------------
// Kernel A (f32 store): register-gather MFMA message MLP, NO atomics.
// 128 threads = 2 waves; wave owns 16 edges x all 128 outputs.
// (verbatim round-9 passing kernel)
// ---------------------------------------------------------------------------
#define MTE 32

__global__ __launch_bounds__(128, 2) void tgn_msg_f32(
    const float* __restrict__ memory,
    const float* __restrict__ last_update,
    const float* __restrict__ timestamps,
    const float* __restrict__ edge_features,
    const float* __restrict__ msg_b,
    const float* __restrict__ time_w,
    const float* __restrict__ time_b,
    const int*   __restrict__ src,
    const int*   __restrict__ dst,
    const short* __restrict__ wfm,
    float* __restrict__ msgf)
{
    const int tid  = threadIdx.x;
    const int wv   = tid >> 6;
    const int l    = tid & 63;
    const int lrow = l & 15;
    const int lkg  = l >> 4;
    const int e0   = blockIdx.x * MTE + wv * 16;
    const int e    = e0 + lrow;

    const int sid = src[e];
    const int did = dst[e];
    const float dt = timestamps[e] - last_update[sid];

    const float* srcm = memory        + (size_t)sid * 128 + lkg * 8;
    const float* dstm = memory        + (size_t)did * 128 + lkg * 8;
    const float* ef   = edge_features + (size_t)e   * 128 + lkg * 8;
    float4 bufS[8], bufD[8], bufE[8];
#pragma unroll
    for (int s = 0; s < 4; ++s) {
        bufS[2 * s]     = *reinterpret_cast<const float4*>(srcm + s * 32);
        bufS[2 * s + 1] = *reinterpret_cast<const float4*>(srcm + s * 32 + 4);
        bufD[2 * s]     = *reinterpret_cast<const float4*>(dstm + s * 32);
        bufD[2 * s + 1] = *reinterpret_cast<const float4*>(dstm + s * 32 + 4);
        bufE[2 * s]     = *reinterpret_cast<const float4*>(ef + s * 32);
        bufE[2 * s + 1] = *reinterpret_cast<const float4*>(ef + s * 32 + 4);
    }

    bf16x8 afr[16];
#pragma unroll
    for (int s = 12; s < 16; ++s) {
        int k0 = s * 32 + lkg * 8;
        float4 lo, hi;
#pragma unroll
        for (int j = 0; j < 8; ++j) {
            int k = k0 + j;
            float v = 0.0f;
            if (k < RAW_DIM) {
                int t = k - 384;
                v = __cosf(fmaf(dt, time_w[t], time_b[t]));
            }
            if (j < 4) (&lo.x)[j] = v; else (&hi.x)[j - 4] = v;
        }
        afr[s] = pack8(lo, hi);
    }

#pragma unroll
    for (int s = 0; s < 4; ++s) {
        afr[s]     = pack8(bufS[2 * s], bufS[2 * s + 1]);
        afr[4 + s] = pack8(bufD[2 * s], bufD[2 * s + 1]);
        afr[8 + s] = pack8(bufE[2 * s], bufE[2 * s + 1]);
    }

    f32x4 acc[8];
#pragma unroll
    for (int t = 0; t < 8; ++t) acc[t] = (f32x4){0.f, 0.f, 0.f, 0.f};

#pragma unroll
    for (int s = 0; s < 16; ++s) {
#pragma unroll
        for (int t = 0; t < 8; ++t) {
            bf16x8 B = *reinterpret_cast<const bf16x8*>(
                &wfm[(size_t)(((t * 16 + s) * 64) + l) * 8]);
            acc[t] = __builtin_amdgcn_mfma_f32_16x16x32_bf16(afr[s], B, acc[t], 0, 0, 0);
        }
    }

#pragma unroll
    for (int r = 0; r < 4; ++r) {
        int erow = e0 + lkg * 4 + r;
        float* orow = msgf + (size_t)erow * 128;
#pragma unroll
        for (int t = 0; t < 8; ++t) {
            int j = t * 16 + lrow;
            orow[j] = acc[t][r] + msg_b[j];
        }
    }
}

// ---------------------------------------------------------------------------
// Kernel B (f32 gather): per-node gather of <=CAP message rows (+ overflow),
// f32 mean, then MFMA GRU.  32 nodes/block, 256 threads, 4 waves/EU.
// Changes vs r9: launch_bounds(,4), cvt_pk conversions, mv from LDS,
// staging before gather for load overlap.
// ---------------------------------------------------------------------------
#define GNT 32

__global__ __launch_bounds__(256, 4) void tgn_gru_f32(
    const float* __restrict__ memory,
    const float* __restrict__ last_update,
    const float* __restrict__ timestamps,
    const float* __restrict__ b_ih,
    const float* __restrict__ b_hh,
    const short* __restrict__ wfrag,
    const float* __restrict__ msgf,
    const uint*  __restrict__ idxv,
    const uint*  __restrict__ cnt,
    const uint*  __restrict__ ovf,
    float* __restrict__ out)
{
    __shared__ short X[GNT][264];
    __shared__ float cntS[GNT];

    const int tid = threadIdx.x;
    const int n0 = blockIdx.x * GNT;

    const int nloc = tid >> 3;
    const int p    = tid & 7;
    const int node = n0 + nloc;

    // issue count load early (latency hides under staging)
    const uint c = cnt[node];
    if (p == 0) cntS[nloc] = (float)c;

    // stage memory -> X[:, 128:256] (independent coalesced streams)
#pragma unroll
    for (int it = 0; it < 4; ++it) {
        int i = tid + it * 256;
        int m = i >> 5;
        int c4 = (i & 31) * 4;
        float4 mv = *reinterpret_cast<const float4*>(&memory[(size_t)(n0 + m) * 128 + c4]);
        uint2 u = {cvtpk(mv.x, mv.y), cvtpk(mv.z, mv.w)};
        *reinterpret_cast<uint2*>(&X[m][128 + c4]) = u;
    }

    // gather-aggregate agg -> X[:, 0:128]; 8 threads/node, 16 dims each
    {
        float a[16];
#pragma unroll
        for (int q = 0; q < 16; ++q) a[q] = 0.0f;
        uint cm = (c < CAP) ? c : (uint)CAP;
        for (uint i = 0; i < cm; ++i) {
            uint eid = idxv[(size_t)node * CAP + i];
            const float* row = msgf + (size_t)eid * 128 + p * 16;
            float4 v0 = *reinterpret_cast<const float4*>(row);
            float4 v1 = *reinterpret_cast<const float4*>(row + 4);
            float4 v2 = *reinterpret_cast<const float4*>(row + 8);
            float4 v3 = *reinterpret_cast<const float4*>(row + 12);
            a[0] += v0.x;  a[1] += v0.y;  a[2]  += v0.z;  a[3]  += v0.w;
            a[4] += v1.x;  a[5] += v1.y;  a[6]  += v1.z;  a[7]  += v1.w;
            a[8] += v2.x;  a[9] += v2.y;  a[10] += v2.z;  a[11] += v2.w;
            a[12] += v3.x; a[13] += v3.y; a[14] += v3.z;  a[15] += v3.w;
        }
        if (c > CAP) {                       // rare: scan overflow list
            uint L = ovf[0];
            if (L > OVF_MAX) L = OVF_MAX;
            for (uint i = 0; i < L; ++i) {
                if (ovf[1 + 2 * i] == (uint)node) {
                    uint eid = ovf[2 + 2 * i];
                    const float* row = msgf + (size_t)eid * 128 + p * 16;
                    float4 v0 = *reinterpret_cast<const float4*>(row);
                    float4 v1 = *reinterpret_cast<const float4*>(row + 4);
                    float4 v2 = *reinterpret_cast<const float4*>(row + 8);
                    float4 v3 = *reinterpret_cast<const float4*>(row + 12);
                    a[0] += v0.x;  a[1] += v0.y;  a[2]  += v0.z;  a[3]  += v0.w;
                    a[4] += v1.x;  a[5] += v1.y;  a[6]  += v1.z;  a[7]  += v1.w;
                    a[8] += v2.x;  a[9] += v2.y;  a[10] += v2.z;  a[11] += v2.w;
                    a[12] += v3.x; a[13] += v3.y; a[14] += v3.z;  a[15] += v3.w;
                }
            }
        }
        float inv = (c > 0) ? (1.0f / (float)c) : 0.0f;
#pragma unroll
        for (int q = 0; q < 16; ++q) a[q] *= inv;
        float4 A0 = {a[0], a[1], a[2], a[3]};
        float4 A1 = {a[4], a[5], a[6], a[7]};
        float4 A2 = {a[8], a[9], a[10], a[11]};
        float4 A3 = {a[12], a[13], a[14], a[15]};
        *reinterpret_cast<bf16x8*>(&X[nloc][p * 16])     = pack8(A0, A1);
        *reinterpret_cast<bf16x8*>(&X[nloc][p * 16 + 8]) = pack8(A2, A3);
    }
    __syncthreads();

    const int w    = tid >> 6;
    const int l    = tid & 63;
    const int lrow = l & 15;
    const int lkg  = l >> 4;

    f32x4 acc[4][2][2];   // [quadrant][jt][mt]
#pragma unroll
    for (int q = 0; q < 4; q++)
#pragma unroll
        for (int jt = 0; jt < 2; jt++)
#pragma unroll
            for (int mt = 0; mt < 2; mt++)
                acc[q][jt][mt] = (f32x4){0.f, 0.f, 0.f, 0.f};

    for (int s = 0; s < 8; ++s) {
        bf16x8 A[2];
#pragma unroll
        for (int mt = 0; mt < 2; ++mt)
            A[mt] = *reinterpret_cast<const bf16x8*>(&X[mt * 16 + lrow][s * 32 + lkg * 8]);
#pragma unroll
        for (int q = 0; q < 4; ++q)
#pragma unroll
            for (int jt = 0; jt < 2; ++jt) {
                int t = q * 8 + w * 2 + jt;
                bf16x8 B = *reinterpret_cast<const bf16x8*>(&wfrag[(size_t)(((t * 8 + s) * 64) + l) * 8]);
#pragma unroll
                for (int mt = 0; mt < 2; ++mt)
                    acc[q][jt][mt] = __builtin_amdgcn_mfma_f32_16x16x32_bf16(
                        A[mt], B, acc[q][jt][mt], 0, 0, 0);
            }
    }

    const float ts0 = timestamps[0];

#pragma unroll
    for (int jt = 0; jt < 2; ++jt) {
        int j = w * 32 + jt * 16 + lrow;
        float br  = b_ih[j]       + b_hh[j];
        float bz  = b_ih[128 + j] + b_hh[128 + j];
        float bin = b_ih[256 + j];
        float bhn = b_hh[256 + j];
#pragma unroll
        for (int mt = 0; mt < 2; ++mt) {
#pragma unroll
            for (int r = 0; r < 4; ++r) {
                int mloc = mt * 16 + lkg * 4 + r;
                int nodew = n0 + mloc;
                float rg  = acc[0][jt][mt][r] + br;
                float zg  = acc[1][jt][mt][r] + bz;
                float ing = acc[2][jt][mt][r] + bin;
                float hng = acc[3][jt][mt][r] + bhn;
                float rr = fsigmoid(rg);
                float zz = fsigmoid(zg);
                float nn = ftanh(ing + rr * hng);
                float mv = bf2f((unsigned short)X[mloc][128 + j]);  // staged copy
                float h  = (1.0f - zz) * nn + zz * mv;
                out[(size_t)nodew * 128 + j] = (cntS[mloc] > 0.0f) ? h : mv;
            }
        }
    }

    if (tid < GNT) {
        int noded = n0 + tid;
        out[(size_t)N_NODES * 128 + noded] = (cntS[tid] > 0.0f) ? ts0 : last_update[noded];
    }
}

// ---------------------------------------------------------------------------
// Fallback path (round-7 proven): separate preps + f32 atomics via d_out.
// ---------------------------------------------------------------------------
__global__ __launch_bounds__(256) void tgn_prep_wmsg(
    const float* __restrict__ msgW, short* __restrict__ wf)
{
    int idx = blockIdx.x * 256 + threadIdx.x;
    int j = idx & 7;
    int l = (idx >> 3) & 63;
    int s = (idx >> 9) & 15;
    int t = idx >> 13;
    int n = t * 16 + (l & 15);
    int k = s * 32 + (l >> 4) * 8 + j;
    float v = (k < RAW_DIM) ? msgW[(size_t)n * RAW_DIM + k] : 0.0f;
    wf[idx] = f2bf(v);
}

__global__ __launch_bounds__(256) void tgn_prep_wgru(
    const float* __restrict__ Wih, const float* __restrict__ Whh,
    short* __restrict__ wf)
{
    int idx = blockIdx.x * 256 + threadIdx.x;
    int j = idx & 7;
    int l = (idx >> 3) & 63;
    int s = (idx >> 9) & 7;
    int t = idx >> 12;
    int n = t * 16 + (l & 15);
    int k = s * 32 + (l >> 4) * 8 + j;
    int half = k >> 7;
    int kk = k & 127;
    float v;
    if (n < 256) {
        v = half ? Whh[(size_t)n * 128 + kk] : Wih[(size_t)n * 128 + kk];
    } else if (n < 384) {
        v = half ? 0.0f : Wih[(size_t)n * 128 + kk];
    } else {
        v = half ? Whh[(size_t)(n - 128) * 128 + kk] : 0.0f;
    }
    wf[idx] = f2bf(v);
}

#define TE 32

__global__ __launch_bounds__(256, 2) void tgn_msg_mfma(
    const float* __restrict__ memory,
    const float* __restrict__ last_update,
    const float* __restrict__ timestamps,
    const float* __restrict__ edge_features,
    const float* __restrict__ msg_b,
    const float* __restrict__ time_w,
    const float* __restrict__ time_b,
    const int*   __restrict__ src,
    const int*   __restrict__ dst,
    const short* __restrict__ wfm,
    float* __restrict__ sums,
    float* __restrict__ counts)
{
    __shared__ short X[TE][520];
    __shared__ int   sid[TE];
    __shared__ int   did[TE];
    __shared__ float dtS[TE];

    const int tid = threadIdx.x;
    const int e0  = blockIdx.x * TE;

    if (tid < TE) {
        int s = src[e0 + tid];
        int d = dst[e0 + tid];
        sid[tid] = s;
        did[tid] = d;
        dtS[tid] = timestamps[e0 + tid] - last_update[s];
        atomicAdd(&counts[s], 1.0f);
        atomicAdd(&counts[d], 1.0f);
    }
    __syncthreads();

    for (int i = tid; i < TE * 128; i += 256) {
        int e = i >> 7;
        int c = (i & 127) * 4;
        float4 v;
        if (c < 128) {
            v = *reinterpret_cast<const float4*>(&memory[(size_t)sid[e] * 128 + c]);
        } else if (c < 256) {
            v = *reinterpret_cast<const float4*>(&memory[(size_t)did[e] * 128 + (c - 128)]);
        } else if (c < 384) {
            v = *reinterpret_cast<const float4*>(&edge_features[(size_t)(e0 + e) * 128 + (c - 256)]);
        } else if (c < 484) {
            float dt = dtS[e];
            int t = c - 384;
            v.x = __cosf(fmaf(dt, time_w[t + 0], time_b[t + 0]));
            v.y = __cosf(fmaf(dt, time_w[t + 1], time_b[t + 1]));
            v.z = __cosf(fmaf(dt, time_w[t + 2], time_b[t + 2]));
            v.w = __cosf(fmaf(dt, time_w[t + 3], time_b[t + 3]));
        } else {
            v.x = v.y = v.z = v.w = 0.0f;
        }
        short4 s4;
        s4.x = f2bf(v.x); s4.y = f2bf(v.y); s4.z = f2bf(v.z); s4.w = f2bf(v.w);
        *reinterpret_cast<short4*>(&X[e][c]) = s4;
    }
    __syncthreads();

    const int w    = tid >> 6;
    const int l    = tid & 63;
    const int lrow = l & 15;
    const int lkg  = l >> 4;
    const int et   = w & 1;
    const int nh   = w >> 1;

    f32x4 acc[4];
#pragma unroll
    for (int n = 0; n < 4; n++) acc[n] = (f32x4){0.f, 0.f, 0.f, 0.f};

#pragma unroll 4
    for (int s = 0; s < 16; ++s) {
        bf16x8 A = *reinterpret_cast<const bf16x8*>(&X[et * 16 + lrow][s * 32 + lkg * 8]);
#pragma unroll
        for (int ntl = 0; ntl < 4; ++ntl) {
            int t = nh * 4 + ntl;
            bf16x8 B = *reinterpret_cast<const bf16x8*>(&wfm[(size_t)(((t * 16 + s) * 64) + l) * 8]);
            acc[ntl] = __builtin_amdgcn_mfma_f32_16x16x32_bf16(A, B, acc[ntl], 0, 0, 0);
        }
    }

#pragma unroll
    for (int ntl = 0; ntl < 4; ++ntl) {
        int j = nh * 64 + ntl * 16 + lrow;
        float bias = msg_b[j];
#pragma unroll
        for (int r = 0; r < 4; ++r) {
            int el = et * 16 + lkg * 4 + r;
            float m = acc[ntl][r] + bias;
            atomicAdd(&sums[(size_t)sid[el] * 128 + j], m);
            atomicAdd(&sums[(size_t)did[el] * 128 + j], m);
        }
    }
}

__global__ __launch_bounds__(256, 3) void tgn_gru_mfma(
    const float* __restrict__ memory,
    const float* __restrict__ last_update,
    const float* __restrict__ timestamps,
    const float* __restrict__ b_ih,
    const float* __restrict__ b_hh,
    const short* __restrict__ wfrag,
    float* __restrict__ out)
{
    __shared__ short X[GNT][264];
    __shared__ float cntS[GNT];

    const int tid = threadIdx.x;
    const int n0 = blockIdx.x * GNT;
    const float* sums   = out;
    const float* counts = out + (size_t)N_NODES * 128;

    if (tid < GNT) cntS[tid] = counts[n0 + tid];
    __syncthreads();

    for (int i = tid; i < GNT * 32; i += 256) {
        int m = i >> 5;
        int c = (i & 31) * 4;
        float inv = 1.0f / fmaxf(cntS[m], 1.0f);
        float4 v = *reinterpret_cast<const float4*>(&sums[(size_t)(n0 + m) * 128 + c]);
        short4 a4;
        a4.x = f2bf(v.x * inv); a4.y = f2bf(v.y * inv);
        a4.z = f2bf(v.z * inv); a4.w = f2bf(v.w * inv);
        *reinterpret_cast<short4*>(&X[m][c]) = a4;
        float4 mv = *reinterpret_cast<const float4*>(&memory[(size_t)(n0 + m) * 128 + c]);
        short4 m4;
        m4.x = f2bf(mv.x); m4.y = f2bf(mv.y); m4.z = f2bf(mv.z); m4.w = f2bf(mv.w);
        *reinterpret_cast<short4*>(&X[m][128 + c]) = m4;
    }
    __syncthreads();

    const int w    = tid >> 6;
    const int l    = tid & 63;
    const int lrow = l & 15;
    const int lkg  = l >> 4;

    f32x4 acc[4][2][2];
#pragma unroll
    for (int q = 0; q < 4; q++)
#pragma unroll
        for (int jt = 0; jt < 2; jt++)
#pragma unroll
            for (int mt = 0; mt < 2; mt++)
                acc[q][jt][mt] = (f32x4){0.f, 0.f, 0.f, 0.f};

    for (int s = 0; s < 8; ++s) {
        bf16x8 A[2];
#pragma unroll
        for (int mt = 0; mt < 2; ++mt)
            A[mt] = *reinterpret_cast<const bf16x8*>(&X[mt * 16 + lrow][s * 32 + lkg * 8]);
#pragma unroll
        for (int q = 0; q < 4; ++q)
#pragma unroll
            for (int jt = 0; jt < 2; ++jt) {
                int t = q * 8 + w * 2 + jt;
                bf16x8 B = *reinterpret_cast<const bf16x8*>(&wfrag[(size_t)(((t * 8 + s) * 64) + l) * 8]);
#pragma unroll
                for (int mt = 0; mt < 2; ++mt)
                    acc[q][jt][mt] = __builtin_amdgcn_mfma_f32_16x16x32_bf16(
                        A[mt], B, acc[q][jt][mt], 0, 0, 0);
            }
    }

    const float ts0 = timestamps[0];
#pragma unroll
    for (int jt = 0; jt < 2; ++jt) {
        int j = w * 32 + jt * 16 + lrow;
        float br  = b_ih[j]       + b_hh[j];
        float bz  = b_ih[128 + j] + b_hh[128 + j];
        float bin = b_ih[256 + j];
        float bhn = b_hh[256 + j];
#pragma unroll
        for (int mt = 0; mt < 2; ++mt) {
#pragma unroll
            for (int r = 0; r < 4; ++r) {
                int mloc = mt * 16 + lkg * 4 + r;
                int node = n0 + mloc;
                float rg  = acc[0][jt][mt][r] + br;
                float zg  = acc[1][jt][mt][r] + bz;
                float ing = acc[2][jt][mt][r] + bin;
                float hng = acc[3][jt][mt][r] + bhn;
                float rr = fsigmoid(rg);
                float zz = fsigmoid(zg);
                float nn = ftanh(ing + rr * hng);
                float mv = memory[(size_t)node * 128 + j];
                float h  = (1.0f - zz) * nn + zz * mv;
                out[(size_t)node * 128 + j] = (cntS[mloc] > 0.0f) ? h : mv;
            }
        }
    }
    if (tid < GNT) {
        int node = n0 + tid;
        out[(size_t)N_NODES * 128 + node] = (cntS[tid] > 0.0f) ? ts0 : last_update[node];
    }
}

// ---------------------------------------------------------------------------
extern "C" void kernel_launch(void* const* d_in, const int* in_sizes, int n_in,
                              void* d_out, int out_size, void* d_ws, size_t ws_size,
                              hipStream_t stream) {
    const float* memory        = (const float*)d_in[0];
    const float* last_update   = (const float*)d_in[1];
    const float* timestamps    = (const float*)d_in[2];
    const float* edge_features = (const float*)d_in[3];
    const float* msg_W         = (const float*)d_in[4];
    const float* msg_b         = (const float*)d_in[5];
    const float* gru_W_ih      = (const float*)d_in[6];
    const float* gru_W_hh      = (const float*)d_in[7];
    const float* gru_b_ih      = (const float*)d_in[8];
    const float* gru_b_hh      = (const float*)d_in[9];
    const float* time_w        = (const float*)d_in[10];
    const float* time_b        = (const float*)d_in[11];
    const int*   src           = (const int*)d_in[12];
    const int*   dst           = (const int*)d_in[13];

    float* out = (float*)d_out;
    char* ws = (char*)d_ws;

    const size_t OFF_WGRU = 0;                                   // 256 KB
    const size_t OFF_WMSG = 262144;                              // 128 KB
    const size_t OFF_MSGF = 393216;                              // E*128 f32
    const size_t SZ_MSGF  = (size_t)E_EDGES * 128 * 4;           // 51.2 MB
    const size_t OFF_IDX  = OFF_MSGF + SZ_MSGF;                  // N*CAP u32
    const size_t SZ_IDX   = (size_t)N_NODES * CAP * 4;           // 8 MB
    const size_t OFF_CNT  = OFF_IDX + SZ_IDX;                    // N u32
    const size_t OFF_OVF  = OFF_CNT + (size_t)N_NODES * 4;
    const size_t WS_NEED  = OFF_OVF + 4 + (size_t)OVF_MAX * 8;

    short* wfrag_gru = (short*)(ws + OFF_WGRU);
    short* wfrag_msg = (short*)(ws + OFF_WMSG);

    if (ws_size >= WS_NEED) {
        float* msgf = (float*)(ws + OFF_MSGF);
        uint*  idxv = (uint*)(ws + OFF_IDX);
        uint*  cnt  = (uint*)(ws + OFF_CNT);
        uint*  ovf  = (uint*)(ws + OFF_OVF);

        hipMemsetAsync(ws + OFF_CNT, 0, (size_t)N_NODES * 4 + 16, stream);

        const int TICKET_BLOCKS = (E_EDGES + 255) / 256;         // 391
        tgn_setup<<<768 + TICKET_BLOCKS, 256, 0, stream>>>(
            gru_W_ih, gru_W_hh, wfrag_gru, msg_W, wfrag_msg,
            src, dst, idxv, cnt, ovf);

        tgn_msg_f32<<<E_EDGES / MTE, 128, 0, stream>>>(
            memory, last_update, timestamps, edge_features, msg_b,
            time_w, time_b, src, dst, wfrag_msg, msgf);

        tgn_gru_f32<<<N_NODES / GNT, 256, 0, stream>>>(
            memory, last_update, timestamps, gru_b_ih, gru_b_hh, wfrag_gru,
            msgf, idxv, cnt, ovf, out);
    } else {
        hipMemsetAsync(d_out, 0, (size_t)out_size * sizeof(float), stream);
        float* sums   = out;
        float* counts = out + (size_t)N_NODES * 128;

        tgn_prep_wgru<<<512, 256, 0, stream>>>(gru_W_ih, gru_W_hh, wfrag_gru);
        tgn_prep_wmsg<<<256, 256, 0, stream>>>(msg_W, wfrag_msg);

        tgn_msg_mfma<<<E_EDGES / TE, 256, 0, stream>>>(
            memory, last_update, timestamps, edge_features, msg_b,
            time_w, time_b, src, dst, wfrag_msg, sums, counts);

        tgn_gru_mfma<<<N_NODES / GNT, 256, 0, stream>>>(
            memory, last_update, timestamps, gru_b_ih, gru_b_hh, wfrag_gru, out);
    }
}